// Round 7
// baseline (32.143 us; speedup 1.0000x reference)
//
#include <hip/hip_runtime.h>
#include <hip/hip_bf16.h>
#include <stdint.h>

typedef __attribute__((ext_vector_type(8))) short short8_t;
typedef __attribute__((ext_vector_type(4))) short short4_t;
typedef __attribute__((ext_vector_type(4))) float f32x4;

#define S_DIM   1024
#define D_DIM   64
#define BM      128            // rows per block -> 256 blocks, 1/CU
#define KC      64
#define NCHUNK  (S_DIM / KC)   // 16
#define THREADS 512
#define NBUF    4              // A chunk buffers (fp32, 32 KB each)

typedef const __attribute__((address_space(1))) uint32_t g_u32;
typedef __attribute__((address_space(3))) uint32_t l_u32;

__device__ __forceinline__ ushort f2bf(float f) {
    __hip_bfloat16 h = __float2bfloat16(f);   // RTNE
    return __builtin_bit_cast(ushort, h);
}

// Publish LDS (ds_write) only; global/gll loads stay in flight across barrier.
#define SYNC() do { \
    __builtin_amdgcn_sched_barrier(0); \
    asm volatile("s_waitcnt lgkmcnt(0)"); \
    __builtin_amdgcn_s_barrier(); \
    __builtin_amdgcn_sched_barrier(0); \
} while (0)

__global__ __launch_bounds__(THREADS, 1)
void gemm_sm_kernel(const float* __restrict__ x1,
                    const float* __restrict__ x2,
                    float* __restrict__ out) {
    // A: fp32, filled by global_load_lds (linear dest, SOURCE-swizzled so the
    //    XOR-swizzled read side is conflict-spread).  4 x 32 KB = 128 KB.
    __shared__ float  lds_a[NBUF][BM * KC];
    // B: fragment-contiguous bf16: 8 frags x 1KB, lane*16B linear + f*32B rot.
    //    Reads are minimum-aliasing by construction.  2 x 8 KB.
    __shared__ ushort lds_b[2][8 * 512];

    const int tid = threadIdx.x;
    const int bid = blockIdx.x;
    // XCD-aware: 8 row-tiles of one (b,h) share an XCD's L2 (B panel dedupe)
    const int batch   = (bid & 7) * 4 + (bid >> 6);   // 0..31
    const int rowtile = (bid >> 3) & 7;               // 0..7
    const int row0    = rowtile * BM;

    const float* Abase = x1 + (size_t)batch * (S_DIM * S_DIM) + (size_t)row0 * S_DIM;
    const float* Bbase = x2 + (size_t)batch * (S_DIM * D_DIM);
    float*       Cbase = out + (size_t)batch * (S_DIM * D_DIM) + (size_t)row0 * D_DIM;

    const int w = tid >> 6;   // wave 0..7 -> owns rows w*16..w*16+15
    const int l = tid & 63;
    const int fr = l & 15, fg = l >> 4;

    // ---- A chunk via global_load_lds ----------------------------------
    // LDS dest (linear, HW: uniform base + lane*16B): word = w*1024 + i*256 + l*4
    //   -> r = w*16 + i*4 + (l>>4), kk_lds = (l&15)*4
    // content map: LDS[r][kk_lds] = A[r][kk_lds ^ ((r&7)<<3)]  (pre-swizzled src)
    auto gllA = [&](int t, int buf) {
        #pragma unroll
        for (int i = 0; i < 4; ++i) {
            const int r  = w * 16 + i * 4 + (l >> 4);
            const int kk = ((l & 15) * 4) ^ ((r & 7) << 3);
            const float* src = Abase + (size_t)r * S_DIM + t * KC + kk;
            float* dst = &lds_a[buf][w * 1024 + i * 256];   // wave-uniform
            __builtin_amdgcn_global_load_lds((g_u32*)src, (l_u32*)dst, 16, 0, 0);
        }
    };

    // ---- B path: global (coalesced) -> regs -> frag-contiguous LDS ----
    const int bd  = l;          // d
    const int bk0 = w * 4;      // k-local base (+32 second half)

    auto loadB = [&](int t, float (&B)[8]) {
        const float* bp = Bbase + (size_t)t * KC * D_DIM + bd;
        #pragma unroll
        for (int i = 0; i < 2; ++i)
            #pragma unroll
            for (int j = 0; j < 4; ++j)
                B[i * 4 + j] = bp[(bk0 + 32 * i + j) * D_DIM];
    };
    // value B[k=i*32+w*4+j][d=l]:  frag f = i*4 + (d>>4),
    // lane-in-frag = (w>>1)*16 + (d&15), elem j' = (w&1)*4 + j
    auto storeB = [&](ushort* lb, const float (&B)[8]) {
        const int lfrag16 = (((w >> 1) << 4) | (l & 15)) * 16;
        #pragma unroll
        for (int i = 0; i < 2; ++i) {
            const int f = i * 4 + (l >> 4);
            const int byteoff = f * 1024 + ((lfrag16 + f * 32) & 1023) + (w & 1) * 8;
            short4_t v;
            #pragma unroll
            for (int j = 0; j < 4; ++j) v[j] = (short)f2bf(B[i * 4 + j]);
            *reinterpret_cast<short4_t*>((char*)lb + byteoff) = v;
        }
    };

    f32x4 acc[4];
    #pragma unroll
    for (int nf = 0; nf < 4; ++nf) acc[nf] = f32x4{0.f, 0.f, 0.f, 0.f};

    // A fragment word base (fp32, XOR-swizzled): row*64 + (ks*32+fg*8)^((row&7)<<3)
    int abase[2];
    {
        const int row = w * 16 + fr;
        #pragma unroll
        for (int ks = 0; ks < 2; ++ks)
            abase[ks] = row * 64 + ((ks * 32 + fg * 8) ^ ((row & 7) << 3));
    }

    auto computeC = [&](const float* la, const ushort* lb) {
        short8_t af[2];
        #pragma unroll
        for (int ks = 0; ks < 2; ++ks) {
            f32x4 lo = *reinterpret_cast<const f32x4*>(&la[abase[ks]]);
            f32x4 hi = *reinterpret_cast<const f32x4*>(&la[abase[ks] + 4]);
            #pragma unroll
            for (int j = 0; j < 4; ++j) {
                af[ks][j]     = (short)f2bf(lo[j]);
                af[ks][4 + j] = (short)f2bf(hi[j]);
            }
        }
        #pragma unroll
        for (int ks = 0; ks < 2; ++ks)
            #pragma unroll
            for (int nf = 0; nf < 4; ++nf) {
                const int f = ks * 4 + nf;
                const int byteoff = f * 1024 + ((l * 16 + f * 32) & 1023);
                short8_t bf = *reinterpret_cast<const short8_t*>(
                    (const char*)lb + byteoff);
                acc[nf] = __builtin_amdgcn_mfma_f32_16x16x32_bf16(
                    af[ks], bf, acc[nf], 0, 0, 0);
            }
    };

    float b0[8], b1[8];   // B(t) lives in breg[t&1]

    // ---- prologue: 3-deep A, 2-deep B ---------------------------------
    gllA(0, 0); gllA(1, 1); gllA(2, 2);
    loadB(0, b0); loadB(1, b1);
    storeB(&lds_b[0][0], b0);   // implicit wait B(0) => gll(0..2) retired too
    SYNC();

    // steady state per iter t: issue gll(t+3)+B(t+2); compute(t);
    // storeB(t+1) implicitly waits B(t+1) => gll(t+2) and older retired,
    // leaving gll(t+3)+B(t+2) = 12 loads in flight across the barrier.
    #pragma unroll 1
    for (int t = 0; t < NCHUNK; ++t) {
        const int pe = t & 1;
        if (t + 3 < NCHUNK) gllA(t + 3, (t + 3) & 3);
        if (t + 2 < NCHUNK) loadB(t + 2, pe ? b1 : b0);
        __builtin_amdgcn_sched_barrier(0);   // loads issue before compute
        computeC(&lds_a[t & 3][0], &lds_b[pe][0]);
        if (t + 1 < NCHUNK) {
            storeB(&lds_b[pe ^ 1][0], pe ? b0 : b1);
            SYNC();
        }
    }

    // epilogue: C/D layout col = lane&15, row = (lane>>4)*4 + j  [m89-verified]
    #pragma unroll
    for (int nf = 0; nf < 4; ++nf)
        #pragma unroll
        for (int j = 0; j < 4; ++j) {
            const int r = w * 16 + fg * 4 + j;
            const int c = nf * 16 + fr;
            Cbase[(size_t)r * D_DIM + c] = acc[nf][j];
        }
}

extern "C" void kernel_launch(void* const* d_in, const int* in_sizes, int n_in,
                              void* d_out, int out_size, void* d_ws, size_t ws_size,
                              hipStream_t stream) {
    const float* x1 = (const float*)d_in[0];
    const float* x2 = (const float*)d_in[1];
    float* out = (float*)d_out;
    dim3 grid(256), block(THREADS);
    gemm_sm_kernel<<<grid, block, 0, stream>>>(x1, x2, out);
}

// Round 8
// 27.933 us; speedup vs baseline: 1.1507x; 1.1507x over previous
//
#include <hip/hip_runtime.h>
#include <hip/hip_bf16.h>

typedef __attribute__((ext_vector_type(8))) short short8_t;
typedef __attribute__((ext_vector_type(4))) short short4_t;
typedef __attribute__((ext_vector_type(4))) float f32x4;

#define S_DIM   1024
#define D_DIM   64
#define BM      128            // rows per block -> 256 blocks, 1/CU
#define KC      128            // k per chunk -> 512B bursts, 8 chunks
#define NCHUNK  (S_DIM / KC)   // 8
#define THREADS 512

__device__ __forceinline__ ushort f2bf(float f) {
    __hip_bfloat16 h = __float2bfloat16(f);   // RTNE
    return __builtin_bit_cast(ushort, h);
}

// Publish LDS writes only; global loads stay in flight across the barrier.
#define SYNC() do { \
    __builtin_amdgcn_sched_barrier(0); \
    asm volatile("s_waitcnt lgkmcnt(0)"); \
    __builtin_amdgcn_s_barrier(); \
    __builtin_amdgcn_sched_barrier(0); \
} while (0)

__global__ __launch_bounds__(THREADS, 1)
void gemm_sm_kernel(const float* __restrict__ x1,
                    const float* __restrict__ x2,
                    float* __restrict__ out) {
    __shared__ ushort lds_a[2][BM * KC];       // 2 x 32 KB, XOR-swizzled (R6)
    // B: fragment-contiguous bf16: 16 frags x 1KB, lane*16B linear + f*32B rot.
    // Wave reads one contiguous 1KB block per frag -> zero bank conflicts.
    __shared__ ushort lds_b[2][16 * 512];      // 2 x 16 KB

    const int tid = threadIdx.x;
    const int bid = blockIdx.x;
    // XCD-aware: 8 row-tiles of one (b,h) share an XCD's L2 (B panel reuse)
    const int batch   = (bid & 7) * 4 + (bid >> 6);   // 0..31
    const int rowtile = (bid >> 3) & 7;               // 0..7
    const int row0    = rowtile * BM;

    const float* Abase = x1 + (size_t)batch * (S_DIM * S_DIM) + (size_t)row0 * S_DIM;
    const float* Bbase = x2 + (size_t)batch * (S_DIM * D_DIM);
    float*       Cbase = out + (size_t)batch * (S_DIM * D_DIM) + (size_t)row0 * D_DIM;

    const int w = tid >> 6;   // wave 0..7 -> owns rows w*16..w*16+15
    const int l = tid & 63;
    const int fr = l & 15, fg = l >> 4;

    // ---- A staging (R6 verbatim): linear-burst map, 512B contiguous bursts
    const int arow  = tid >> 5;          // row 0..15 (+ i*16 per round)
    const int acol4 = (tid & 31) * 4;    // float offset within 512B window
    const float* aptr = Abase + (size_t)arow * S_DIM + acol4;
    const int aw_u16 = (arow * KC + acol4) ^ ((arow & 7) << 3);  // + i*16*KC

    // ---- B staging: lane = d, wave picks k-groups ----
    const int bd  = l;
    const int bk0 = w * 4;               // k-local base (+i*32)

    // ---- A fragment indices (R6 verbatim) ----
    int aidx[4];
    {
        const int row = w * 16 + fr;
        #pragma unroll
        for (int ks = 0; ks < 4; ++ks)
            aidx[ks] = (row * KC + ks * 32 + fg * 8) ^ ((row & 7) << 3);
    }

    // 1-deep register prefetch
    float4 Ar[8];
    float  Br[16];

    auto loadA = [&](int t) {
        const float* p = aptr + t * KC;
        #pragma unroll
        for (int i = 0; i < 8; ++i)
            Ar[i] = *reinterpret_cast<const float4*>(p + (size_t)i * 16 * S_DIM);
    };
    auto loadB = [&](int t) {
        const float* bp = Bbase + (size_t)t * KC * D_DIM + bd;
        #pragma unroll
        for (int i = 0; i < 4; ++i)
            #pragma unroll
            for (int j = 0; j < 4; ++j)
                Br[i * 4 + j] = bp[(size_t)(bk0 + i * 32 + j) * D_DIM];
    };
    auto storeA = [&](ushort* la) {
        #pragma unroll
        for (int i = 0; i < 8; ++i) {
            short4_t v;
            v[0] = (short)f2bf(Ar[i].x); v[1] = (short)f2bf(Ar[i].y);
            v[2] = (short)f2bf(Ar[i].z); v[3] = (short)f2bf(Ar[i].w);
            *reinterpret_cast<short4_t*>(&la[aw_u16 + i * 16 * KC]) = v;
        }
    };
    // value Br[i*4+j] = B[k = i*32 + w*4 + j][d = l]
    //   frag f = i*4 + (l>>4)  (ks=i, nf=d>>4)
    //   lane-in-frag = (w>>1)*16 + (l&15), elem j' = (w&1)*4 + j
    // layout: byte = f*1024 + ((lane_in_frag*16 + f*32) & 1023) + j'*2
    auto storeB = [&](ushort* lb) {
        const int lfrag16 = (((w >> 1) << 4) | (l & 15)) * 16;
        #pragma unroll
        for (int i = 0; i < 4; ++i) {
            const int f = i * 4 + (l >> 4);
            const int byteoff = f * 1024 + ((lfrag16 + f * 32) & 1023) + (w & 1) * 8;
            short4_t v;
            #pragma unroll
            for (int j = 0; j < 4; ++j) v[j] = (short)f2bf(Br[i * 4 + j]);
            *reinterpret_cast<short4_t*>((char*)lb + byteoff) = v;
        }
    };

    f32x4 acc[4];
    #pragma unroll
    for (int nf = 0; nf < 4; ++nf) acc[nf] = f32x4{0.f, 0.f, 0.f, 0.f};

    auto compute = [&](const ushort* la, const ushort* lb) {
        short8_t af[4];
        #pragma unroll
        for (int ks = 0; ks < 4; ++ks)
            af[ks] = *reinterpret_cast<const short8_t*>(&la[aidx[ks]]);
        #pragma unroll
        for (int ks = 0; ks < 4; ++ks)
            #pragma unroll
            for (int nf = 0; nf < 4; ++nf) {
                const int f = ks * 4 + nf;
                const int byteoff = f * 1024 + ((l * 16 + f * 32) & 1023);
                short8_t bf = *reinterpret_cast<const short8_t*>(
                    (const char*)lb + byteoff);
                acc[nf] = __builtin_amdgcn_mfma_f32_16x16x32_bf16(
                    af[ks], bf, acc[nf], 0, 0, 0);
            }
    };

    // ---- pipeline (R6 verbatim): issue t+1 early, compute t, publish t+1
    loadA(0); loadB(0);
    storeA(&lds_a[0][0]); storeB(&lds_b[0][0]);
    SYNC();

    #pragma unroll 1
    for (int t = 0; t < NCHUNK; ++t) {
        if (t + 1 < NCHUNK) { loadA(t + 1); loadB(t + 1); }
        __builtin_amdgcn_sched_barrier(0);   // loads issue before compute
        compute(&lds_a[t & 1][0], &lds_b[t & 1][0]);
        __builtin_amdgcn_sched_barrier(0);   // MFMAs stay above the vmcnt wait
        if (t + 1 < NCHUNK) {
            storeA(&lds_a[(t + 1) & 1][0]);
            storeB(&lds_b[(t + 1) & 1][0]);
            SYNC();
        }
    }

    // epilogue: C/D layout col = lane&15, row = (lane>>4)*4 + j  [m89-verified]
    #pragma unroll
    for (int nf = 0; nf < 4; ++nf)
        #pragma unroll
        for (int j = 0; j < 4; ++j) {
            const int r = w * 16 + fg * 4 + j;
            const int c = nf * 16 + fr;
            Cbase[(size_t)r * D_DIM + c] = acc[nf][j];
        }
}

extern "C" void kernel_launch(void* const* d_in, const int* in_sizes, int n_in,
                              void* d_out, int out_size, void* d_ws, size_t ws_size,
                              hipStream_t stream) {
    const float* x1 = (const float*)d_in[0];
    const float* x2 = (const float*)d_in[1];
    float* out = (float*)d_out;
    dim3 grid(256), block(THREADS);
    gemm_sm_kernel<<<grid, block, 0, stream>>>(x1, x2, out);
}